// Round 13
// baseline (174.941 us; speedup 1.0000x reference)
//
#include <hip/hip_runtime.h>
#include <hip/hip_bf16.h>
#include <stdint.h>

#define B_DIM 8
#define C_DIM 512
#define N_DIM 3136
#define NP    3200   // N padded to 25*128
#define BK    32
#define NKS   (C_DIM / BK)         // 16 K-steps
#define NT    25                   // NP/128
#define NTRI  (NT * (NT + 1) / 2)  // 325 lower-tri block tiles

typedef short bf16x8 __attribute__((ext_vector_type(8)));
typedef float f32x4  __attribute__((ext_vector_type(4)));

__device__ __forceinline__ void gload16(const void* g, void* l) {
  __builtin_amdgcn_global_load_lds(
      (const __attribute__((address_space(1))) void*)g,
      (__attribute__((address_space(3))) void*)l, 16, 0, 0);
}

__device__ __forceinline__ float bf2f(ushort u) {
  union { uint32_t i; float f; } c;
  c.i = ((uint32_t)u) << 16;
  return c.f;
}

__device__ __forceinline__ ushort f2bf(float f) {
  __hip_bfloat16 h = __float2bfloat16(f);
  return *(ushort*)&h;
}

// x[b][c][n] f32 -> kt[b][n][c] bf16 (n padded to NP, pad rows zero).
__global__ __launch_bounds__(256) void k_transpose(const float* __restrict__ x,
                                                   ushort* __restrict__ kt) {
  __shared__ float tile[64][33];
  const int b  = blockIdx.z;
  const int n0 = blockIdx.x * 32;
  const int c0 = blockIdx.y * 64;
  const int tx = threadIdx.x;
  const int ty = threadIdx.y;
#pragma unroll
  for (int j = 0; j < 8; ++j) {
    int c = c0 + ty + 8 * j;
    int n = n0 + tx;
    float v = (n < N_DIM) ? x[((size_t)b * C_DIM + c) * N_DIM + n] : 0.0f;
    tile[ty + 8 * j][tx] = v;
  }
  __syncthreads();
  const int tid = ty * 32 + tx;
  const int r = tid >> 5;
  const int p = tid & 31;
#pragma unroll
  for (int i = 0; i < 4; ++i) {
    int nl = r + 8 * i;
    int n = n0 + nl;
    uint32_t u = (uint32_t)f2bf(tile[2 * p][nl]) |
                 ((uint32_t)f2bf(tile[2 * p + 1][nl]) << 16);
    *(uint32_t*)(kt + ((size_t)b * NP + n) * C_DIM + c0 + 2 * p) = u;
  }
}

// sq[b*NP+n] = sum_c kt[b][n][c]^2 (fp32 accum over bf16 values).
__global__ __launch_bounds__(256) void k_norms(const ushort* __restrict__ kt,
                                               float* __restrict__ sq) {
  const int row  = blockIdx.x * 4 + (threadIdx.x >> 6);
  const int lane = threadIdx.x & 63;
  const ushort* p = kt + (size_t)row * C_DIM + lane * 8;
  bf16x8 v = *(const bf16x8*)p;
  float s = 0.0f;
#pragma unroll
  for (int j = 0; j < 8; ++j) {
    float f = bf2f((ushort)v[j]);
    s += f * f;
  }
#pragma unroll
  for (int m = 32; m >= 1; m >>= 1) s += __shfl_xor(s, m);
  if (lane == 0) sq[row] = s;
}

// Symmetric GEMM, lower-tri tiles, nt output stores. B staged in LDS
// (depth-2 counted-vmcnt pipeline, 3 x 8KB buffers); A-fragments loaded
// DIRECTLY global->VGPR from the L2-resident kt panel (halves LDS read
// and write traffic vs R12). A-loads are issued BEFORE the B-stage gloads
// each iter so the compiler's pre-MFMA wait is vmcnt(2) (B stays in
// flight). Mirror epilogue uses raw s_barrier + lgkmcnt only (nt stores
// stay in flight across passes).
__global__ __launch_bounds__(256) void k_gemm(const ushort* __restrict__ kt,
                                              const float* __restrict__ sq,
                                              float* __restrict__ out) {
  // union: 3 B staging buffers (24KB) in main loop; [64][132] f32 tr (33.8KB)
  __shared__ __attribute__((aligned(16))) char smem[64 * 132 * 4];
  float* tr = (float*)smem;

  const int id = blockIdx.x;
  const int b = id & 7;
  const int t = id >> 3;
  int bx = (int)((sqrtf(8.0f * (float)t + 1.0f) - 1.0f) * 0.5f);
  while ((bx + 1) * (bx + 2) / 2 <= t) ++bx;
  while (bx * (bx + 1) / 2 > t) --bx;
  const int by = t - bx * (bx + 1) / 2;

  const int n0 = bx * 128;  // rows (A tile)
  const int m0 = by * 128;  // cols (B tile)
  const int tid  = threadIdx.x;
  const int wave = tid >> 6;
  const int lane = tid & 63;
  const ushort* ktb = kt + (size_t)b * NP * C_DIM;

  const int wr = (wave >> 1) * 64;
  const int wc = (wave & 1) * 64;
  const int koff = lane >> 4;
  const int rl = lane & 15;

  // B staging addresses (K-invariant)
  const int q    = wave * 64 + lane;
  const int row0 = q >> 2;
  const int lk0  = (q & 3) ^ ((q >> 3) & 3);
  const int row1 = (q + 256) >> 2;
  const int lk1  = (q & 3) ^ (((q + 256) >> 3) & 3);
  const ushort* gB0 = ktb + (size_t)(m0 + row0) * C_DIM + lk0 * 8;
  const ushort* gB1 = ktb + (size_t)(m0 + row1) * C_DIM + lk1 * 8;
  const int ldOff0 = q * 16;
  const int ldOff1 = (q + 256) * 16;

  // A-fragment direct-load base pointers (per-lane row, k advances by BK)
  const ushort* aP[4];
#pragma unroll
  for (int mi = 0; mi < 4; ++mi)
    aP[mi] = ktb + (size_t)(n0 + wr + mi * 16 + rl) * C_DIM + koff * 8;

  f32x4 acc[4][4];
#pragma unroll
  for (int mi = 0; mi < 4; ++mi)
#pragma unroll
    for (int ni = 0; ni < 4; ++ni)
      acc[mi][ni] = (f32x4){0.f, 0.f, 0.f, 0.f};

#define STAGE_B(ksi, buf)                                                   \
  do {                                                                      \
    const int kb = (ksi) * BK;                                              \
    char* base = smem + (buf) * 8192;                                       \
    gload16(gB0 + kb, base + ldOff0);                                       \
    gload16(gB1 + kb, base + ldOff1);                                       \
  } while (0)

  STAGE_B(0, 0);
  STAGE_B(1, 1);

  for (int ks = 0; ks < NKS; ++ks) {
    // B-buf[ks] complete; B-buf[ks+1]'s 2 loads stay in flight.
    if (ks + 2 < NKS) asm volatile("s_waitcnt vmcnt(2)" ::: "memory");
    else              asm volatile("s_waitcnt vmcnt(0)" ::: "memory");
    __builtin_amdgcn_s_barrier();

    // A-frags for THIS iter, direct from global (L2-resident panel).
    bf16x8 aF[4];
#pragma unroll
    for (int mi = 0; mi < 4; ++mi)
      aF[mi] = *(const bf16x8*)(aP[mi] + ks * BK);
    asm volatile("" ::: "memory");  // pin A-loads above the B-stage gloads

    if (ks + 2 < NKS) STAGE_B(ks + 2, (ks + 2) % 3);

    const char* tB = smem + (ks % 3) * 8192;
    bf16x8 bF[4];
#pragma unroll
    for (int ni = 0; ni < 4; ++ni) {
      int row  = wc + ni * 16 + rl;
      int phys = koff ^ ((row >> 1) & 3);
      bF[ni] = *(const bf16x8*)(tB + row * 64 + phys * 16);
    }
#pragma unroll
    for (int mi = 0; mi < 4; ++mi)
#pragma unroll
      for (int ni = 0; ni < 4; ++ni)
        acc[mi][ni] = __builtin_amdgcn_mfma_f32_16x16x32_bf16(
            aF[mi], bF[ni], acc[mi][ni], 0, 0, 0);
  }
#undef STAGE_B

  // ---- epilogue: normalize ----
  const float* sqb = sq + b * NP;
  float rrow[4][4], rcol[4];
#pragma unroll
  for (int mi = 0; mi < 4; ++mi)
#pragma unroll
    for (int r = 0; r < 4; ++r) {
      float s = sqb[n0 + wr + mi * 16 + koff * 4 + r];
      rrow[mi][r] = 1.0f / fmaxf(sqrtf(s), 1e-8f);
    }
#pragma unroll
  for (int ni = 0; ni < 4; ++ni) {
    float s = sqb[m0 + wc + ni * 16 + rl];
    rcol[ni] = 1.0f / fmaxf(sqrtf(s), 1e-8f);
  }
#pragma unroll
  for (int mi = 0; mi < 4; ++mi)
#pragma unroll
    for (int ni = 0; ni < 4; ++ni)
#pragma unroll
      for (int r = 0; r < 4; ++r)
        acc[mi][ni][r] *= rrow[mi][r] * rcol[ni];

  float* outb = out + (size_t)b * N_DIM * N_DIM;

  // direct write: out[n0+row][m0+col] — coalesced, non-temporal
#pragma unroll
  for (int mi = 0; mi < 4; ++mi) {
#pragma unroll
    for (int ni = 0; ni < 4; ++ni) {
#pragma unroll
      for (int r = 0; r < 4; ++r) {
        int row = n0 + wr + mi * 16 + koff * 4 + r;
        int col = m0 + wc + ni * 16 + rl;
        if (row < N_DIM && col < N_DIM)
          __builtin_nontemporal_store(acc[mi][ni][r],
                                      outb + (size_t)row * N_DIM + col);
      }
    }
  }

  // mirror write via LDS transpose, two 64-col passes. Raw barriers with
  // lgkmcnt-only waits: the in-flight nt stores are NOT drained here.
  if (bx != by) {
#pragma unroll
    for (int h = 0; h < 2; ++h) {
      asm volatile("s_waitcnt lgkmcnt(0)" ::: "memory");
      __builtin_amdgcn_s_barrier();   // prior readers of tr (or K-loop) done
      if ((wave & 1) == h) {
#pragma unroll
        for (int ni = 0; ni < 4; ++ni) {
          int colL = ni * 16 + rl;  // 0..63
#pragma unroll
          for (int mi = 0; mi < 4; ++mi) {
            int row = wr + mi * 16 + koff * 4;  // 16B-aligned
            *(f32x4*)(tr + colL * 132 + row) = acc[mi][ni];
          }
        }
      }
      asm volatile("s_waitcnt lgkmcnt(0)" ::: "memory");
      __builtin_amdgcn_s_barrier();   // tr writes visible
#pragma unroll
      for (int it = 0; it < 8; ++it) {
        int i  = it * 8 + (tid >> 5);   // local mirror row 0..63
        int j4 = (tid & 31) * 4;        // col chunk
        int gm = m0 + h * 64 + i;       // global row (= original col)
        int gn = n0 + j4;               // global col (= original row)
        if (gm < N_DIM && gn < N_DIM) {
          f32x4 v = *(const f32x4*)(tr + i * 132 + j4);
          __builtin_nontemporal_store(
              v, (f32x4*)(outb + (size_t)gm * N_DIM + gn));
        }
      }
    }
  }
}

extern "C" void kernel_launch(void* const* d_in, const int* in_sizes, int n_in,
                              void* d_out, int out_size, void* d_ws, size_t ws_size,
                              hipStream_t stream) {
  const float* x = (const float*)d_in[0];
  float* out = (float*)d_out;

  ushort* kt = (ushort*)d_ws;
  float* sq = (float*)((char*)d_ws + (size_t)B_DIM * NP * C_DIM * 2);

  dim3 gT(NP / 32, C_DIM / 64, B_DIM);  // 100,8,8
  k_transpose<<<gT, dim3(32, 8), 0, stream>>>(x, kt);

  k_norms<<<B_DIM * NP / 4, 256, 0, stream>>>(kt, sq);

  k_gemm<<<NTRI * B_DIM, 256, 0, stream>>>(kt, sq, out);  // 2600 blocks
}

// Round 14
// 118.499 us; speedup vs baseline: 1.4763x; 1.4763x over previous
//
#include <hip/hip_runtime.h>
#include <hip/hip_bf16.h>
#include <stdint.h>

#define B_DIM 8
#define C_DIM 512
#define N_DIM 3136
#define NP    3200   // N padded to 25*128
#define BK    32
#define NKS   (C_DIM / BK)         // 16 K-steps
#define NT    25                   // NP/128
#define NTRI  (NT * (NT + 1) / 2)  // 325 lower-tri block tiles

typedef short bf16x8 __attribute__((ext_vector_type(8)));
typedef float f32x4  __attribute__((ext_vector_type(4)));

__device__ __forceinline__ void gload16(const void* g, void* l) {
  __builtin_amdgcn_global_load_lds(
      (const __attribute__((address_space(1))) void*)g,
      (__attribute__((address_space(3))) void*)l, 16, 0, 0);
}

__device__ __forceinline__ float bf2f(ushort u) {
  union { uint32_t i; float f; } c;
  c.i = ((uint32_t)u) << 16;
  return c.f;
}

__device__ __forceinline__ ushort f2bf(float f) {
  __hip_bfloat16 h = __float2bfloat16(f);
  return *(ushort*)&h;
}

// x[b][c][n] f32 -> kt[b][n][c] bf16 (n padded to NP, pad rows zero).
__global__ __launch_bounds__(256) void k_transpose(const float* __restrict__ x,
                                                   ushort* __restrict__ kt) {
  __shared__ float tile[64][33];
  const int b  = blockIdx.z;
  const int n0 = blockIdx.x * 32;
  const int c0 = blockIdx.y * 64;
  const int tx = threadIdx.x;
  const int ty = threadIdx.y;
#pragma unroll
  for (int j = 0; j < 8; ++j) {
    int c = c0 + ty + 8 * j;
    int n = n0 + tx;
    float v = (n < N_DIM) ? x[((size_t)b * C_DIM + c) * N_DIM + n] : 0.0f;
    tile[ty + 8 * j][tx] = v;
  }
  __syncthreads();
  const int tid = ty * 32 + tx;
  const int r = tid >> 5;
  const int p = tid & 31;
#pragma unroll
  for (int i = 0; i < 4; ++i) {
    int nl = r + 8 * i;
    int n = n0 + nl;
    uint32_t u = (uint32_t)f2bf(tile[2 * p][nl]) |
                 ((uint32_t)f2bf(tile[2 * p + 1][nl]) << 16);
    *(uint32_t*)(kt + ((size_t)b * NP + n) * C_DIM + c0 + 2 * p) = u;
  }
}

// sq[b*NP+n] = sum_c kt[b][n][c]^2 (fp32 accum over bf16 values).
__global__ __launch_bounds__(256) void k_norms(const ushort* __restrict__ kt,
                                               float* __restrict__ sq) {
  const int row  = blockIdx.x * 4 + (threadIdx.x >> 6);
  const int lane = threadIdx.x & 63;
  const ushort* p = kt + (size_t)row * C_DIM + lane * 8;
  bf16x8 v = *(const bf16x8*)p;
  float s = 0.0f;
#pragma unroll
  for (int j = 0; j < 8; ++j) {
    float f = bf2f((ushort)v[j]);
    s += f * f;
  }
#pragma unroll
  for (int m = 32; m >= 1; m >>= 1) s += __shfl_xor(s, m);
  if (lane == 0) sq[row] = s;
}

// Symmetric GEMM, lower-tri tiles, nt output stores. R12 main loop verbatim:
// depth-2 counted-vmcnt pipeline, 3 LDS buffers, per iter
//   vmcnt(4) -> s_barrier -> STAGE(ks+2) -> ds_read+MFMA from buf[ks].
// SINGLE change vs R12: mirror-epilogue barriers are s_barrier+lgkmcnt(0)
// only (no vmcnt drain) — in-flight nt direct-stores are NOT waited on.
// Safe: final 2 K-iters used vmcnt(0) so no staging load can land in tr;
// outstanding nt stores target global memory, never LDS.
__global__ __launch_bounds__(256) void k_gemm(const ushort* __restrict__ kt,
                                              const float* __restrict__ sq,
                                              float* __restrict__ out) {
  // 3 staging buffers (3 x 16KB = 48KB); mirror tr [64][132] f32 (33.8KB) unioned
  __shared__ __attribute__((aligned(16))) char smem[49152];
  float* tr = (float*)smem;

  const int id = blockIdx.x;
  const int b = id & 7;
  const int t = id >> 3;
  int bx = (int)((sqrtf(8.0f * (float)t + 1.0f) - 1.0f) * 0.5f);
  while ((bx + 1) * (bx + 2) / 2 <= t) ++bx;
  while (bx * (bx + 1) / 2 > t) --bx;
  const int by = t - bx * (bx + 1) / 2;

  const int n0 = bx * 128;  // rows (A tile)
  const int m0 = by * 128;  // cols (B tile)
  const int tid  = threadIdx.x;
  const int wave = tid >> 6;
  const int lane = tid & 63;
  const ushort* ktb = kt + (size_t)b * NP * C_DIM;

  const int wr = (wave >> 1) * 64;
  const int wc = (wave & 1) * 64;
  const int koff = lane >> 4;
  const int rl = lane & 15;

  // per-thread staging addresses (K-invariant)
  const int q    = wave * 64 + lane;
  const int row0 = q >> 2;
  const int lk0  = (q & 3) ^ ((q >> 3) & 3);
  const int row1 = (q + 256) >> 2;
  const int lk1  = (q & 3) ^ (((q + 256) >> 3) & 3);
  const ushort* gA0 = ktb + (size_t)(n0 + row0) * C_DIM + lk0 * 8;
  const ushort* gA1 = ktb + (size_t)(n0 + row1) * C_DIM + lk1 * 8;
  const ushort* gB0 = ktb + (size_t)(m0 + row0) * C_DIM + lk0 * 8;
  const ushort* gB1 = ktb + (size_t)(m0 + row1) * C_DIM + lk1 * 8;
  const int ldOff0 = q * 16;
  const int ldOff1 = (q + 256) * 16;

  f32x4 acc[4][4];
#pragma unroll
  for (int mi = 0; mi < 4; ++mi)
#pragma unroll
    for (int ni = 0; ni < 4; ++ni)
      acc[mi][ni] = (f32x4){0.f, 0.f, 0.f, 0.f};

#define STAGE(ksi, buf)                                                     \
  do {                                                                      \
    const int kb = (ksi) * BK;                                              \
    char* base = smem + (buf) * 16384;                                      \
    gload16(gA0 + kb, base + ldOff0);                                       \
    gload16(gA1 + kb, base + ldOff1);                                       \
    gload16(gB0 + kb, base + 8192 + ldOff0);                                \
    gload16(gB1 + kb, base + 8192 + ldOff1);                                \
  } while (0)

  STAGE(0, 0);   // 4 loads
  STAGE(1, 1);   // 4 loads

  for (int ks = 0; ks < NKS; ++ks) {
    if (ks + 2 < NKS) asm volatile("s_waitcnt vmcnt(4)" ::: "memory");
    else              asm volatile("s_waitcnt vmcnt(0)" ::: "memory");
    __builtin_amdgcn_s_barrier();
    if (ks + 2 < NKS) STAGE(ks + 2, (ks + 2) % 3);

    const char* tA = smem + (ks % 3) * 16384;
    const char* tB = tA + 8192;
    bf16x8 aF[4], bF[4];
#pragma unroll
    for (int mi = 0; mi < 4; ++mi) {
      int row  = wr + mi * 16 + rl;
      int phys = koff ^ ((row >> 1) & 3);
      aF[mi] = *(const bf16x8*)(tA + row * 64 + phys * 16);
    }
#pragma unroll
    for (int ni = 0; ni < 4; ++ni) {
      int row  = wc + ni * 16 + rl;
      int phys = koff ^ ((row >> 1) & 3);
      bF[ni] = *(const bf16x8*)(tB + row * 64 + phys * 16);
    }
#pragma unroll
    for (int mi = 0; mi < 4; ++mi)
#pragma unroll
      for (int ni = 0; ni < 4; ++ni)
        acc[mi][ni] = __builtin_amdgcn_mfma_f32_16x16x32_bf16(
            aF[mi], bF[ni], acc[mi][ni], 0, 0, 0);
  }
#undef STAGE

  // ---- epilogue: normalize ----
  const float* sqb = sq + b * NP;
  float rrow[4][4], rcol[4];
#pragma unroll
  for (int mi = 0; mi < 4; ++mi)
#pragma unroll
    for (int r = 0; r < 4; ++r) {
      float s = sqb[n0 + wr + mi * 16 + koff * 4 + r];
      rrow[mi][r] = 1.0f / fmaxf(sqrtf(s), 1e-8f);
    }
#pragma unroll
  for (int ni = 0; ni < 4; ++ni) {
    float s = sqb[m0 + wc + ni * 16 + rl];
    rcol[ni] = 1.0f / fmaxf(sqrtf(s), 1e-8f);
  }
#pragma unroll
  for (int mi = 0; mi < 4; ++mi)
#pragma unroll
    for (int ni = 0; ni < 4; ++ni)
#pragma unroll
      for (int r = 0; r < 4; ++r)
        acc[mi][ni][r] *= rrow[mi][r] * rcol[ni];

  float* outb = out + (size_t)b * N_DIM * N_DIM;

  // direct write: out[n0+row][m0+col] — coalesced, non-temporal, fire-and-forget
#pragma unroll
  for (int mi = 0; mi < 4; ++mi) {
#pragma unroll
    for (int ni = 0; ni < 4; ++ni) {
#pragma unroll
      for (int r = 0; r < 4; ++r) {
        int row = n0 + wr + mi * 16 + koff * 4 + r;
        int col = m0 + wc + ni * 16 + rl;
        if (row < N_DIM && col < N_DIM)
          __builtin_nontemporal_store(acc[mi][ni][r],
                                      outb + (size_t)row * N_DIM + col);
      }
    }
  }

  // mirror write via LDS transpose, two 64-col passes. Barriers are
  // s_barrier + lgkmcnt(0) ONLY — in-flight nt stores are not drained.
  if (bx != by) {
#pragma unroll
    for (int h = 0; h < 2; ++h) {
      asm volatile("s_waitcnt lgkmcnt(0)" ::: "memory");
      __builtin_amdgcn_s_barrier();   // prior tr readers (K-loop / pass 0) done
      if ((wave & 1) == h) {
#pragma unroll
        for (int ni = 0; ni < 4; ++ni) {
          int colL = ni * 16 + rl;  // 0..63
#pragma unroll
          for (int mi = 0; mi < 4; ++mi) {
            int row = wr + mi * 16 + koff * 4;  // 16B-aligned
            *(f32x4*)(tr + colL * 132 + row) = acc[mi][ni];
          }
        }
      }
      asm volatile("s_waitcnt lgkmcnt(0)" ::: "memory");
      __builtin_amdgcn_s_barrier();   // tr writes visible to all waves
#pragma unroll
      for (int it = 0; it < 8; ++it) {
        int i  = it * 8 + (tid >> 5);   // local mirror row 0..63
        int j4 = (tid & 31) * 4;        // col chunk
        int gm = m0 + h * 64 + i;       // global row (= original col)
        int gn = n0 + j4;               // global col (= original row)
        if (gm < N_DIM && gn < N_DIM) {
          f32x4 v = *(const f32x4*)(tr + i * 132 + j4);
          __builtin_nontemporal_store(
              v, (f32x4*)(outb + (size_t)gm * N_DIM + gn));
        }
      }
    }
  }
}

extern "C" void kernel_launch(void* const* d_in, const int* in_sizes, int n_in,
                              void* d_out, int out_size, void* d_ws, size_t ws_size,
                              hipStream_t stream) {
  const float* x = (const float*)d_in[0];
  float* out = (float*)d_out;

  ushort* kt = (ushort*)d_ws;
  float* sq = (float*)((char*)d_ws + (size_t)B_DIM * NP * C_DIM * 2);

  dim3 gT(NP / 32, C_DIM / 64, B_DIM);  // 100,8,8
  k_transpose<<<gT, dim3(32, 8), 0, stream>>>(x, kt);

  k_norms<<<B_DIM * NP / 4, 256, 0, stream>>>(kt, sq);

  k_gemm<<<NTRI * B_DIM, 256, 0, stream>>>(kt, sq, out);  // 2600 blocks
}

// Round 16
// 116.789 us; speedup vs baseline: 1.4979x; 1.0146x over previous
//
#include <hip/hip_runtime.h>
#include <hip/hip_bf16.h>
#include <stdint.h>

#define B_DIM 8
#define C_DIM 512
#define N_DIM 3136
#define NP    3200   // N padded to 25*128
#define BK    32
#define NKS   (C_DIM / BK)         // 16 K-steps
#define NT    25                   // NP/128
#define NTRI  (NT * (NT + 1) / 2)  // 325 lower-tri block tiles

typedef short bf16x8 __attribute__((ext_vector_type(8)));
typedef float f32x4  __attribute__((ext_vector_type(4)));

__device__ __forceinline__ void gload16(const void* g, void* l) {
  __builtin_amdgcn_global_load_lds(
      (const __attribute__((address_space(1))) void*)g,
      (__attribute__((address_space(3))) void*)l, 16, 0, 0);
}

__device__ __forceinline__ float bf2f(ushort u) {
  union { uint32_t i; float f; } c;
  c.i = ((uint32_t)u) << 16;
  return c.f;
}

__device__ __forceinline__ ushort f2bf(float f) {
  __hip_bfloat16 h = __float2bfloat16(f);
  return *(ushort*)&h;
}

// x[b][c][n] f32 -> kt[b][n][c] bf16 (n padded to NP, pad rows zero),
// PLUS per-block partial row-norms: part[b][n][cblk] = sum of this block's
// 64-c chunk of bf16(x)^2. Threads sharing row n are the 32 consecutive
// lanes p=0..31 of a 32-aligned half-wave -> shfl_xor (m<=16) reduce.
__global__ __launch_bounds__(256) void k_transpose(const float* __restrict__ x,
                                                   ushort* __restrict__ kt,
                                                   float* __restrict__ part) {
  __shared__ float tile[64][33];
  const int b  = blockIdx.z;
  const int n0 = blockIdx.x * 32;
  const int c0 = blockIdx.y * 64;
  const int tx = threadIdx.x;
  const int ty = threadIdx.y;
#pragma unroll
  for (int j = 0; j < 8; ++j) {
    int c = c0 + ty + 8 * j;
    int n = n0 + tx;
    float v = (n < N_DIM) ? x[((size_t)b * C_DIM + c) * N_DIM + n] : 0.0f;
    tile[ty + 8 * j][tx] = v;
  }
  __syncthreads();
  const int tid = ty * 32 + tx;
  const int r = tid >> 5;   // n-sub 0..7
  const int p = tid & 31;   // c-pair 0..31
  float ss[4];
#pragma unroll
  for (int i = 0; i < 4; ++i) {
    int nl = r + 8 * i;
    int n = n0 + nl;
    ushort u0 = f2bf(tile[2 * p][nl]);
    ushort u1 = f2bf(tile[2 * p + 1][nl]);
    *(uint32_t*)(kt + ((size_t)b * NP + n) * C_DIM + c0 + 2 * p) =
        (uint32_t)u0 | ((uint32_t)u1 << 16);
    float f0 = bf2f(u0), f1 = bf2f(u1);
    ss[i] = f0 * f0 + f1 * f1;
  }
#pragma unroll
  for (int i = 0; i < 4; ++i) {
    float s = ss[i];
#pragma unroll
    for (int m = 16; m >= 1; m >>= 1) s += __shfl_xor(s, m);
    if (p == 0)
      part[((size_t)b * NP + n0 + r + 8 * i) * 8 + blockIdx.y] = s;
  }
}

// sq[row] = sum of the 8 c-block partials (25600 rows, trivial).
__global__ __launch_bounds__(256) void k_sqred(const float* __restrict__ part,
                                               float* __restrict__ sq) {
  const int row = blockIdx.x * 256 + threadIdx.x;
  const float* p = part + (size_t)row * 8;
  float s = 0.0f;
#pragma unroll
  for (int j = 0; j < 8; ++j) s += p[j];
  sq[row] = s;
}

// Symmetric GEMM, lower-tri tiles — R14 VERBATIM: nt output stores,
// depth-2 counted-vmcnt pipeline (3 x 16KB buffers), lgkm-only mirror
// barriers.
__global__ __launch_bounds__(256) void k_gemm(const ushort* __restrict__ kt,
                                              const float* __restrict__ sq,
                                              float* __restrict__ out) {
  __shared__ __attribute__((aligned(16))) char smem[49152];
  float* tr = (float*)smem;

  const int id = blockIdx.x;
  const int b = id & 7;
  const int t = id >> 3;
  int bx = (int)((sqrtf(8.0f * (float)t + 1.0f) - 1.0f) * 0.5f);
  while ((bx + 1) * (bx + 2) / 2 <= t) ++bx;
  while (bx * (bx + 1) / 2 > t) --bx;
  const int by = t - bx * (bx + 1) / 2;

  const int n0 = bx * 128;  // rows (A tile)
  const int m0 = by * 128;  // cols (B tile)
  const int tid  = threadIdx.x;
  const int wave = tid >> 6;
  const int lane = tid & 63;
  const ushort* ktb = kt + (size_t)b * NP * C_DIM;

  const int wr = (wave >> 1) * 64;
  const int wc = (wave & 1) * 64;
  const int koff = lane >> 4;
  const int rl = lane & 15;

  const int q    = wave * 64 + lane;
  const int row0 = q >> 2;
  const int lk0  = (q & 3) ^ ((q >> 3) & 3);
  const int row1 = (q + 256) >> 2;
  const int lk1  = (q & 3) ^ (((q + 256) >> 3) & 3);
  const ushort* gA0 = ktb + (size_t)(n0 + row0) * C_DIM + lk0 * 8;
  const ushort* gA1 = ktb + (size_t)(n0 + row1) * C_DIM + lk1 * 8;
  const ushort* gB0 = ktb + (size_t)(m0 + row0) * C_DIM + lk0 * 8;
  const ushort* gB1 = ktb + (size_t)(m0 + row1) * C_DIM + lk1 * 8;
  const int ldOff0 = q * 16;
  const int ldOff1 = (q + 256) * 16;

  f32x4 acc[4][4];
#pragma unroll
  for (int mi = 0; mi < 4; ++mi)
#pragma unroll
    for (int ni = 0; ni < 4; ++ni)
      acc[mi][ni] = (f32x4){0.f, 0.f, 0.f, 0.f};

#define STAGE(ksi, buf)                                                     \
  do {                                                                      \
    const int kb = (ksi) * BK;                                              \
    char* base = smem + (buf) * 16384;                                      \
    gload16(gA0 + kb, base + ldOff0);                                       \
    gload16(gA1 + kb, base + ldOff1);                                       \
    gload16(gB0 + kb, base + 8192 + ldOff0);                                \
    gload16(gB1 + kb, base + 8192 + ldOff1);                                \
  } while (0)

  STAGE(0, 0);
  STAGE(1, 1);

  for (int ks = 0; ks < NKS; ++ks) {
    if (ks + 2 < NKS) asm volatile("s_waitcnt vmcnt(4)" ::: "memory");
    else              asm volatile("s_waitcnt vmcnt(0)" ::: "memory");
    __builtin_amdgcn_s_barrier();
    if (ks + 2 < NKS) STAGE(ks + 2, (ks + 2) % 3);

    const char* tA = smem + (ks % 3) * 16384;
    const char* tB = tA + 8192;
    bf16x8 aF[4], bF[4];
#pragma unroll
    for (int mi = 0; mi < 4; ++mi) {
      int row  = wr + mi * 16 + rl;
      int phys = koff ^ ((row >> 1) & 3);
      aF[mi] = *(const bf16x8*)(tA + row * 64 + phys * 16);
    }
#pragma unroll
    for (int ni = 0; ni < 4; ++ni) {
      int row  = wc + ni * 16 + rl;
      int phys = koff ^ ((row >> 1) & 3);
      bF[ni] = *(const bf16x8*)(tB + row * 64 + phys * 16);
    }
#pragma unroll
    for (int mi = 0; mi < 4; ++mi)
#pragma unroll
      for (int ni = 0; ni < 4; ++ni)
        acc[mi][ni] = __builtin_amdgcn_mfma_f32_16x16x32_bf16(
            aF[mi], bF[ni], acc[mi][ni], 0, 0, 0);
  }
#undef STAGE

  // ---- epilogue: normalize ----
  const float* sqb = sq + b * NP;
  float rrow[4][4], rcol[4];
#pragma unroll
  for (int mi = 0; mi < 4; ++mi)
#pragma unroll
    for (int r = 0; r < 4; ++r) {
      float s = sqb[n0 + wr + mi * 16 + koff * 4 + r];
      rrow[mi][r] = 1.0f / fmaxf(sqrtf(s), 1e-8f);
    }
#pragma unroll
  for (int ni = 0; ni < 4; ++ni) {
    float s = sqb[m0 + wc + ni * 16 + rl];
    rcol[ni] = 1.0f / fmaxf(sqrtf(s), 1e-8f);
  }
#pragma unroll
  for (int mi = 0; mi < 4; ++mi)
#pragma unroll
    for (int ni = 0; ni < 4; ++ni)
#pragma unroll
      for (int r = 0; r < 4; ++r)
        acc[mi][ni][r] *= rrow[mi][r] * rcol[ni];

  float* outb = out + (size_t)b * N_DIM * N_DIM;

  // direct write: coalesced, non-temporal, fire-and-forget
#pragma unroll
  for (int mi = 0; mi < 4; ++mi) {
#pragma unroll
    for (int ni = 0; ni < 4; ++ni) {
#pragma unroll
      for (int r = 0; r < 4; ++r) {
        int row = n0 + wr + mi * 16 + koff * 4 + r;
        int col = m0 + wc + ni * 16 + rl;
        if (row < N_DIM && col < N_DIM)
          __builtin_nontemporal_store(acc[mi][ni][r],
                                      outb + (size_t)row * N_DIM + col);
      }
    }
  }

  // mirror write via LDS transpose, two 64-col passes, lgkm-only barriers
  if (bx != by) {
#pragma unroll
    for (int h = 0; h < 2; ++h) {
      asm volatile("s_waitcnt lgkmcnt(0)" ::: "memory");
      __builtin_amdgcn_s_barrier();
      if ((wave & 1) == h) {
#pragma unroll
        for (int ni = 0; ni < 4; ++ni) {
          int colL = ni * 16 + rl;  // 0..63
#pragma unroll
          for (int mi = 0; mi < 4; ++mi) {
            int row = wr + mi * 16 + koff * 4;  // 16B-aligned
            *(f32x4*)(tr + colL * 132 + row) = acc[mi][ni];
          }
        }
      }
      asm volatile("s_waitcnt lgkmcnt(0)" ::: "memory");
      __builtin_amdgcn_s_barrier();
#pragma unroll
      for (int it = 0; it < 8; ++it) {
        int i  = it * 8 + (tid >> 5);   // local mirror row 0..63
        int j4 = (tid & 31) * 4;        // col chunk
        int gm = m0 + h * 64 + i;       // global row (= original col)
        int gn = n0 + j4;               // global col (= original row)
        if (gm < N_DIM && gn < N_DIM) {
          f32x4 v = *(const f32x4*)(tr + i * 132 + j4);
          __builtin_nontemporal_store(
              v, (f32x4*)(outb + (size_t)gm * N_DIM + gn));
        }
      }
    }
  }
}

extern "C" void kernel_launch(void* const* d_in, const int* in_sizes, int n_in,
                              void* d_out, int out_size, void* d_ws, size_t ws_size,
                              hipStream_t stream) {
  const float* x = (const float*)d_in[0];
  float* out = (float*)d_out;

  // ws: kt bf16 [8][3200][512] (32.8MB) | sq f32 [25600] | part f32 [25600][8]
  ushort* kt = (ushort*)d_ws;
  float* sq   = (float*)((char*)d_ws + (size_t)B_DIM * NP * C_DIM * 2);
  float* part = sq + (size_t)B_DIM * NP;

  dim3 gT(NP / 32, C_DIM / 64, B_DIM);  // 100,8,8
  k_transpose<<<gT, dim3(32, 8), 0, stream>>>(x, kt, part);

  k_sqred<<<B_DIM * NP / 256, 256, 0, stream>>>(part, sq);

  k_gemm<<<NTRI * B_DIM, 256, 0, stream>>>(kt, sq, out);  // 2600 blocks
}